// Round 3
// baseline (1485.960 us; speedup 1.0000x reference)
//
#include <hip/hip_runtime.h>
#include <hip/hip_bf16.h>

// MoE FFN: B=4 T=2048 D=1024 F=4096 E=8 top-2, fp32 in/out.
// fp32 router -> expert buckets -> bf16 MFMA grouped GEMMs.
// R2: XOR-swizzled LDS granule placement (bank conflicts = 0, verified).
// R3: depth-1 dbuf + __syncthreads no-op (barrier drains vmcnt(0)).
// R4: counted vmcnt + 3-buf + nontemporal h + XCD swizzle: ffn1 628->468us,
//     MfmaUtil 26%, FETCH 557->253MB. 128^2 2-phase structure ceiling reached.
// R5: (a) 8-wave 4-phase K-tile=64 pipelined template (256x128 ffn1 with dual
//     B operands, 256x256 ffn2), per-phase: {2 wave-GLDS prefetch of next
//     K-tile chunk, ds_read frags, 16 MFMA in setprio(1), lgkmcnt(0), barrier},
//     vmcnt(4) every 2 phases, never vmcnt(0) in steady state. Grouped-GEMM
//     8ph vs 2ph measured +29% elsewhere at same K.
//     (b) k_tr rewrite: 64x64 tile, float4 reads / ushort8 writes (was
//     4B-read/64B-chunk-write, ~1.5TB/s, est ~450us total).

#define NTOK 8192
#define DMODEL 1024
#define FDIM 4096
#define NEXP 8
#define NT1 (DMODEL/64)   // 16 K-tiles for ffn1
#define NT2 (FDIM/64)     // 64 K-tiles for ffn2

typedef __attribute__((ext_vector_type(8))) short s8v;   // 8 x bf16 (4 VGPR)
typedef __attribute__((ext_vector_type(4))) float f4v;   // MFMA accumulator
typedef __attribute__((ext_vector_type(8))) unsigned short us8;

__device__ __forceinline__ int imin(int a, int b){ return a < b ? a : b; }

// fp32 -> bf16 round-to-nearest-even
__device__ __forceinline__ unsigned short f2b(float f){
  union { float f; unsigned u; } v; v.f = f;
  unsigned r = v.u + 0x7fffu + ((v.u >> 16) & 1u);
  return (unsigned short)(r >> 16);
}

__device__ __forceinline__ f4v mfma16(s8v a, s8v b, f4v c){
  return __builtin_amdgcn_mfma_f32_16x16x32_bf16(a, b, c, 0, 0, 0);
}

// async global->LDS, 16B/lane; LDS dest = wave-uniform base + lane*16
#define GLDS16(gp, lp) __builtin_amdgcn_global_load_lds(                      \
    (const __attribute__((address_space(1))) void*)(gp),                      \
    (__attribute__((address_space(3))) void*)(lp), 16, 0, 0)

#define WAIT_LGK  asm volatile("s_waitcnt lgkmcnt(0)" ::: "memory")
#define WAIT_V4   asm volatile("s_waitcnt vmcnt(4) lgkmcnt(0)" ::: "memory")
#define WAIT_V0   asm volatile("s_waitcnt vmcnt(0) lgkmcnt(0)" ::: "memory")
#define BAR       __builtin_amdgcn_s_barrier()

// LDS swizzle: 64B rows (4 x 16B granules). Source granule g of row r lives at
// LDS position g ^ ((r>>1)&3). Staging lane (r = base + lane>>2, pos = lane&3)
// fetches source granule (lane&3) ^ (((lane>>2)>>1)&3); fragment read at row lm
// uses position quad ^ ((lm>>1)&3). Row-base terms are multiples of 4 rows so
// they drop out of the swizzle. Bank math: bank = (row&1)*16 + pos*4 + phase ->
// 2 lanes/bank = free (verified SQ_LDS_BANK_CONFLICT = 0).

// ---------------- fp32 -> bf16 elementwise (x) ----------------
__global__ void k_cvt(const float4* __restrict__ in, ushort4* __restrict__ out, int n4){
  int i = blockIdx.x * blockDim.x + threadIdx.x;
  int st = gridDim.x * blockDim.x;
  for(; i < n4; i += st){
    float4 v = in[i];
    ushort4 o;
    o.x = f2b(v.x); o.y = f2b(v.y); o.z = f2b(v.z); o.w = f2b(v.w);
    out[i] = o;
  }
}

// ---------------- fp32 [e][R][C] -> bf16 [e][C][R] transpose, 64x64 tiles ----
// reads float4/lane (1KB/wave/instr), writes ushort8/lane (128B per 8 lanes).
__global__ void k_tr(const float* __restrict__ in, unsigned short* __restrict__ out,
                     int R, int C){
  __shared__ float tile[64][65];
  const float* src = in + (size_t)blockIdx.z * R * C;
  unsigned short* dst = out + (size_t)blockIdx.z * R * C;
  int bx = blockIdx.x * 64, by = blockIdx.y * 64;
  int tid = threadIdx.x;
  int tx = tid & 15, ty = tid >> 4;        // tx: float4 slot, ty: row 0..15
  #pragma unroll
  for(int i = 0; i < 64; i += 16){
    float4 v = *(const float4*)&src[(size_t)(by + ty + i) * C + bx + tx*4];
    tile[ty + i][tx*4 + 0] = v.x; tile[ty + i][tx*4 + 1] = v.y;
    tile[ty + i][tx*4 + 2] = v.z; tile[ty + i][tx*4 + 3] = v.w;
  }
  __syncthreads();
  int oc = tid & 7, orow = tid >> 3;       // oc: ushort8 slot, orow 0..31
  #pragma unroll
  for(int i = 0; i < 64; i += 32){
    int r = orow + i;                      // output row = original col bx+r
    us8 o;
    #pragma unroll
    for(int j = 0; j < 8; j++) o[j] = f2b(tile[oc*8 + j][r]);
    *(us8*)&dst[(size_t)(bx + r) * R + by + oc*8] = o;
  }
}

// ---------------- router: fp32 logits -> softmax -> top2 -> renorm ----------------
__global__ void k_router(const float* __restrict__ x, const float* __restrict__ gw,
                         int* __restrict__ route_e, float* __restrict__ route_w,
                         int* __restrict__ counts){
  int lane = threadIdx.x & 63;
  int t = blockIdx.x * 4 + (threadIdx.x >> 6);   // one wave per token
  const float* xr = x + (size_t)t * DMODEL;
  float acc[NEXP];
  #pragma unroll
  for(int e = 0; e < NEXP; e++) acc[e] = 0.f;
  for(int d = lane; d < DMODEL; d += 64){
    float xv = xr[d];
    const float* g = gw + d * NEXP;
    #pragma unroll
    for(int e = 0; e < NEXP; e++) acc[e] += xv * g[e];
  }
  #pragma unroll
  for(int off = 32; off > 0; off >>= 1){
    #pragma unroll
    for(int e = 0; e < NEXP; e++) acc[e] += __shfl_down(acc[e], off, 64);
  }
  if(lane == 0){
    float mx = acc[0];
    #pragma unroll
    for(int e = 1; e < NEXP; e++) mx = fmaxf(mx, acc[e]);
    float p[NEXP];
    #pragma unroll
    for(int e = 0; e < NEXP; e++) p[e] = expf(acc[e] - mx);
    int i0 = 0;
    #pragma unroll
    for(int e = 1; e < NEXP; e++) if(p[e] > p[i0]) i0 = e;     // first-max (jax tie rule)
    int i1 = (i0 == 0) ? 1 : 0;
    #pragma unroll
    for(int e = 0; e < NEXP; e++) if(e != i0 && p[e] > p[i1]) i1 = e;
    float inv = 1.f / (p[i0] + p[i1]);           // softmax denom cancels in ratio
    route_e[2*t]   = i0; route_e[2*t+1] = i1;
    route_w[2*t]   = p[i0] * inv;
    route_w[2*t+1] = p[i1] * inv;
    atomicAdd(&counts[i0], 1); atomicAdd(&counts[i1], 1);
  }
}

__global__ void k_scan(const int* __restrict__ counts, int* __restrict__ offsets,
                       int* __restrict__ cursor){
  if(threadIdx.x == 0){
    int o = 0;
    for(int e = 0; e < NEXP; e++){ offsets[e] = o; o += counts[e]; cursor[e] = 0; }
    offsets[NEXP] = o;
  }
}

__global__ void k_fill(const int* __restrict__ route_e, const float* __restrict__ route_w,
                       const int* __restrict__ offsets, int* __restrict__ cursor,
                       int* __restrict__ pair_tok, float* __restrict__ pair_wt,
                       int* __restrict__ t2p){
  int t = blockIdx.x * blockDim.x + threadIdx.x;
  if(t >= NTOK) return;
  #pragma unroll
  for(int k = 0; k < 2; k++){
    int e = route_e[2*t + k];
    int pos = atomicAdd(&cursor[e], 1);
    int gidx = offsets[e] + pos;
    pair_tok[gidx] = t;
    pair_wt[gidx] = route_w[2*t + k];
    t2p[2*t + k] = gidx;
  }
}

// ---------------- stage A: h = silu(x@w1) * (x@w3) ----------------
// tile 256M x 128N, K-tile 64 (2 kk-chunks of 32), 8 waves (4M x 2N),
// per-wave out 64x64 per matrix. 4 phases/K-tile, 16 MFMA each, dbuf LDS.
__global__ __launch_bounds__(512, 2) void k_ffn1(
    const unsigned short* __restrict__ xb,
    const unsigned short* __restrict__ w1t,   // [e][f][d] bf16
    const unsigned short* __restrict__ w3t,
    const int* __restrict__ counts, const int* __restrict__ offsets,
    const int* __restrict__ pair_tok,
    unsigned short* __restrict__ h)           // [pair][f] bf16
{
  // XCD swizzle: nwg = 64*32*8 = 16384, chunk 2048
  unsigned lin = blockIdx.x + ((blockIdx.y + (blockIdx.z << 5)) << 6);
  unsigned swz = ((lin & 7u) << 11) | (lin >> 3);
  int e  = swz >> 11;
  int bx = swz & 63;
  int by = (swz >> 6) & 31;

  int cnt = counts[e];
  int m0 = bx * 256;
  if(m0 >= cnt) return;
  int off = offsets[e];
  int n0 = by * 128;

  __shared__ short As[2][2][256][32];    // [buf][kk][row][64B]
  __shared__ short B1s[2][2][128][32];
  __shared__ short B3s[2][2][128][32];
  __shared__ int stok[256];

  int tid = threadIdx.x;
  if(tid < 256) stok[tid] = pair_tok[off + imin(m0 + tid, cnt - 1)];
  __syncthreads();

  int w = tid >> 6, lane = tid & 63;
  int lr = lane >> 2, g = lane & 3;
  int gs = (g ^ ((lr >> 1) & 3)) * 16;       // swizzled source granule byte off

  int rA0 = w*32 + lr, rA1 = rA0 + 16;       // A staging rows (per wave 32)
  int rB  = w*16 + lr;                       // B staging row (per wave 16/kk)
  const char* pA0 = (const char*)xb + (size_t)stok[rA0] * (DMODEL*2) + gs;
  const char* pA1 = (const char*)xb + (size_t)stok[rA1] * (DMODEL*2) + gs;
  const char* pB1 = (const char*)w1t + ((size_t)e*FDIM + n0 + rB) * (DMODEL*2) + gs;
  const char* pB3 = (const char*)w3t + ((size_t)e*FDIM + n0 + rB) * (DMODEL*2) + gs;

  auto stageA = [&](int kt, int kk, int buf){
    int kb = kt*128 + kk*64;
    GLDS16(pA0 + kb, &As[buf][kk][w*32][0]);
    GLDS16(pA1 + kb, &As[buf][kk][w*32 + 16][0]);
  };
  auto stageB = [&](int kt, int kk, int buf){
    int kb = kt*128 + kk*64;
    GLDS16(pB1 + kb, &B1s[buf][kk][w*16][0]);
    GLDS16(pB3 + kb, &B3s[buf][kk][w*16][0]);
  };

  f4v zero = {0.f, 0.f, 0.f, 0.f};
  f4v acc1[4][4], acc3[4][4];
  #pragma unroll
  for(int i = 0; i < 4; i++)
    #pragma unroll
    for(int j = 0; j < 4; j++){ acc1[i][j] = zero; acc3[i][j] = zero; }

  int wm = w & 3, wn = w >> 2;               // 4M x 2N wave grid
  int lm = lane & 15, quad = lane >> 4;
  int rp = (quad ^ ((lm >> 1) & 3)) * 8;     // swizzled LDS read pos (shorts)

  // prologue: tile 0 fully issued; certify kk0 (kk1's 4 loads stay in flight)
  stageA(0, 0, 0); stageB(0, 0, 0); stageA(0, 1, 0); stageB(0, 1, 0);
  WAIT_V4; BAR;

  s8v b1f[4], b3f[4];
  for(int t = 0; t < NT1; ++t){
    int buf = t & 1;
    bool last = (t == NT1 - 1);

    // ---- P0: kk0, mi 0-1 ----
    if(!last) stageA(t+1, 0, buf^1);
    {
      s8v a0 = *(const s8v*)&As[buf][0][wm*64 +  0 + lm][rp];
      s8v a1 = *(const s8v*)&As[buf][0][wm*64 + 16 + lm][rp];
      #pragma unroll
      for(int ni = 0; ni < 4; ni++){
        b1f[ni] = *(const s8v*)&B1s[buf][0][wn*64 + ni*16 + lm][rp];
        b3f[ni] = *(const s8v*)&B3s[buf][0][wn*64 + ni*16 + lm][rp];
      }
      __builtin_amdgcn_s_setprio(1);
      #pragma unroll
      for(int ni = 0; ni < 4; ni++){
        acc1[0][ni] = mfma16(a0, b1f[ni], acc1[0][ni]);
        acc3[0][ni] = mfma16(a0, b3f[ni], acc3[0][ni]);
        acc1[1][ni] = mfma16(a1, b1f[ni], acc1[1][ni]);
        acc3[1][ni] = mfma16(a1, b3f[ni], acc3[1][ni]);
      }
      __builtin_amdgcn_s_setprio(0);
    }
    WAIT_LGK; BAR;

    // ---- P1: kk0, mi 2-3 (reuse b1f/b3f) ----
    if(!last) stageB(t+1, 0, buf^1);
    {
      s8v a2 = *(const s8v*)&As[buf][0][wm*64 + 32 + lm][rp];
      s8v a3 = *(const s8v*)&As[buf][0][wm*64 + 48 + lm][rp];
      __builtin_amdgcn_s_setprio(1);
      #pragma unroll
      for(int ni = 0; ni < 4; ni++){
        acc1[2][ni] = mfma16(a2, b1f[ni], acc1[2][ni]);
        acc3[2][ni] = mfma16(a2, b3f[ni], acc3[2][ni]);
        acc1[3][ni] = mfma16(a3, b1f[ni], acc1[3][ni]);
        acc3[3][ni] = mfma16(a3, b3f[ni], acc3[3][ni]);
      }
      __builtin_amdgcn_s_setprio(0);
    }
    if(!last) WAIT_V4; else WAIT_V0;     // certify current tile's kk1
    BAR;

    // ---- P2: kk1, mi 0-1 ----
    if(!last) stageA(t+1, 1, buf^1);
    {
      s8v a0 = *(const s8v*)&As[buf][1][wm*64 +  0 + lm][rp];
      s8v a1 = *(const s8v*)&As[buf][1][wm*64 + 16 + lm][rp];
      #pragma unroll
      for(int ni = 0; ni < 4; ni++){
        b1f[ni] = *(const s8v*)&B1s[buf][1][wn*64 + ni*16 + lm][rp];
        b3f[ni] = *(const s8v*)&B3s[buf][1][wn*64 + ni*16 + lm][rp];
      }
      __builtin_amdgcn_s_setprio(1);
      #pragma unroll
      for(int ni = 0; ni < 4; ni++){
        acc1[0][ni] = mfma16(a0, b1f[ni], acc1[0][ni]);
        acc3[0][ni] = mfma16(a0, b3f[ni], acc3[0][ni]);
        acc1[1][ni] = mfma16(a1, b1f[ni], acc1[1][ni]);
        acc3[1][ni] = mfma16(a1, b3f[ni], acc3[1][ni]);
      }
      __builtin_amdgcn_s_setprio(0);
    }
    WAIT_LGK; BAR;

    // ---- P3: kk1, mi 2-3 ----
    if(!last) stageB(t+1, 1, buf^1);
    {
      s8v a2 = *(const s8v*)&As[buf][1][wm*64 + 32 + lm][rp];
      s8v a3 = *(const s8v*)&As[buf][1][wm*64 + 48 + lm][rp];
      __builtin_amdgcn_s_setprio(1);
      #pragma unroll
      for(int ni = 0; ni < 4; ni++){
        acc1[2][ni] = mfma16(a2, b1f[ni], acc1[2][ni]);
        acc3[2][ni] = mfma16(a2, b3f[ni], acc3[2][ni]);
        acc1[3][ni] = mfma16(a3, b1f[ni], acc1[3][ni]);
        acc3[3][ni] = mfma16(a3, b3f[ni], acc3[3][ni]);
      }
      __builtin_amdgcn_s_setprio(0);
    }
    if(!last){ WAIT_V4; BAR; }           // certify next tile's kk0
  }

  // epilogue: SwiGLU, nontemporal bf16 h store. C/D: col=lane&15, row=quad*4+reg
  #pragma unroll
  for(int mi = 0; mi < 4; mi++){
    int prb = m0 + wm*64 + mi*16 + quad*4;
    #pragma unroll
    for(int i = 0; i < 4; i++){
      int pr = prb + i;
      if(pr < cnt){
        size_t hrow = (size_t)(off + pr) * FDIM + n0 + wn*64 + lm;
        #pragma unroll
        for(int ni = 0; ni < 4; ni++){
          float p = acc1[mi][ni][i];
          float q = acc3[mi][ni][i];
          float hv = (p / (1.f + __expf(-p))) * q;   // silu(p)*q
          __builtin_nontemporal_store((unsigned short)f2b(hv), &h[hrow + ni*16]);
        }
      }
    }
  }
}

// ---------------- stage B: pout[pair] = wt * (h @ w2) ----------------
// tile 256M x 256N, K-tile 64, 8 waves (2M x 4N), per-wave out 128x64.
__global__ __launch_bounds__(512, 2) void k_ffn2(
    const unsigned short* __restrict__ h,     // [pair][f] bf16
    const unsigned short* __restrict__ w2t,   // [e][d][f] bf16
    const int* __restrict__ counts, const int* __restrict__ offsets,
    const float* __restrict__ pair_wt,
    float* __restrict__ pout)                 // [pair][d] fp32 (aliases w1t)
{
  // XCD swizzle: nwg = 64*4*8 = 2048, chunk 256
  unsigned lin = blockIdx.x + ((blockIdx.y + (blockIdx.z << 2)) << 6);
  unsigned swz = ((lin & 7u) << 8) | (lin >> 3);
  int e  = swz >> 8;
  int bx = swz & 63;
  int by = (swz >> 6) & 3;

  int cnt = counts[e];
  int m0 = bx * 256;
  if(m0 >= cnt) return;
  int off = offsets[e];
  int n0 = by * 256;

  __shared__ short As[2][2][256][32];
  __shared__ short Bs[2][2][256][32];

  int tid = threadIdx.x, w = tid >> 6, lane = tid & 63;
  int lr = lane >> 2, g = lane & 3;
  int gs = (g ^ ((lr >> 1) & 3)) * 16;

  int rA0 = w*32 + lr, rA1 = rA0 + 16;
  int pr0 = imin(m0 + rA0, cnt - 1), pr1 = imin(m0 + rA1, cnt - 1);
  const char* pA0 = (const char*)h + (size_t)(off + pr0) * (FDIM*2) + gs;
  const char* pA1 = (const char*)h + (size_t)(off + pr1) * (FDIM*2) + gs;
  const char* pB0 = (const char*)w2t + ((size_t)e*DMODEL + n0 + rA0) * (FDIM*2) + gs;
  const char* pB1 = (const char*)w2t + ((size_t)e*DMODEL + n0 + rA1) * (FDIM*2) + gs;

  auto stageA = [&](int kt, int kk, int buf){
    int kb = kt*128 + kk*64;
    GLDS16(pA0 + kb, &As[buf][kk][w*32][0]);
    GLDS16(pA1 + kb, &As[buf][kk][w*32 + 16][0]);
  };
  auto stageB = [&](int kt, int kk, int buf){
    int kb = kt*128 + kk*64;
    GLDS16(pB0 + kb, &Bs[buf][kk][w*32][0]);
    GLDS16(pB1 + kb, &Bs[buf][kk][w*32 + 16][0]);
  };

  f4v zero = {0.f, 0.f, 0.f, 0.f};
  f4v acc[8][4];
  #pragma unroll
  for(int i = 0; i < 8; i++)
    #pragma unroll
    for(int j = 0; j < 4; j++) acc[i][j] = zero;

  int wm = w & 1, wn = w >> 1;               // 2M x 4N wave grid
  int lm = lane & 15, quad = lane >> 4;
  int rp = (quad ^ ((lm >> 1) & 3)) * 8;

  stageA(0, 0, 0); stageB(0, 0, 0); stageA(0, 1, 0); stageB(0, 1, 0);
  WAIT_V4; BAR;

  s8v bf[4];
  for(int t = 0; t < NT2; ++t){
    int buf = t & 1;
    bool last = (t == NT2 - 1);

    // ---- P0: kk0, mi 0-3 ----
    if(!last) stageA(t+1, 0, buf^1);
    {
      s8v af[4];
      #pragma unroll
      for(int mi = 0; mi < 4; mi++)
        af[mi] = *(const s8v*)&As[buf][0][wm*128 + mi*16 + lm][rp];
      #pragma unroll
      for(int ni = 0; ni < 4; ni++)
        bf[ni] = *(const s8v*)&Bs[buf][0][wn*64 + ni*16 + lm][rp];
      __builtin_amdgcn_s_setprio(1);
      #pragma unroll
      for(int mi = 0; mi < 4; mi++)
        #pragma unroll
        for(int ni = 0; ni < 4; ni++)
          acc[mi][ni] = mfma16(af[mi], bf[ni], acc[mi][ni]);
      __builtin_amdgcn_s_setprio(0);
    }
    WAIT_LGK; BAR;

    // ---- P1: kk0, mi 4-7 ----
    if(!last) stageB(t+1, 0, buf^1);
    {
      s8v af[4];
      #pragma unroll
      for(int mi = 0; mi < 4; mi++)
        af[mi] = *(const s8v*)&As[buf][0][wm*128 + (4+mi)*16 + lm][rp];
      __builtin_amdgcn_s_setprio(1);
      #pragma unroll
      for(int mi = 0; mi < 4; mi++)
        #pragma unroll
        for(int ni = 0; ni < 4; ni++)
          acc[4+mi][ni] = mfma16(af[mi], bf[ni], acc[4+mi][ni]);
      __builtin_amdgcn_s_setprio(0);
    }
    if(!last) WAIT_V4; else WAIT_V0;
    BAR;

    // ---- P2: kk1, mi 0-3 ----
    if(!last) stageA(t+1, 1, buf^1);
    {
      s8v af[4];
      #pragma unroll
      for(int mi = 0; mi < 4; mi++)
        af[mi] = *(const s8v*)&As[buf][1][wm*128 + mi*16 + lm][rp];
      #pragma unroll
      for(int ni = 0; ni < 4; ni++)
        bf[ni] = *(const s8v*)&Bs[buf][1][wn*64 + ni*16 + lm][rp];
      __builtin_amdgcn_s_setprio(1);
      #pragma unroll
      for(int mi = 0; mi < 4; mi++)
        #pragma unroll
        for(int ni = 0; ni < 4; ni++)
          acc[mi][ni] = mfma16(af[mi], bf[ni], acc[mi][ni]);
      __builtin_amdgcn_s_setprio(0);
    }
    WAIT_LGK; BAR;

    // ---- P3: kk1, mi 4-7 ----
    if(!last) stageB(t+1, 1, buf^1);
    {
      s8v af[4];
      #pragma unroll
      for(int mi = 0; mi < 4; mi++)
        af[mi] = *(const s8v*)&As[buf][1][wm*128 + (4+mi)*16 + lm][rp];
      __builtin_amdgcn_s_setprio(1);
      #pragma unroll
      for(int mi = 0; mi < 4; mi++)
        #pragma unroll
        for(int ni = 0; ni < 4; ni++)
          acc[4+mi][ni] = mfma16(af[mi], bf[ni], acc[4+mi][ni]);
      __builtin_amdgcn_s_setprio(0);
    }
    if(!last){ WAIT_V4; BAR; }
  }

  // epilogue: scale by gate weight, nontemporal store to per-pair row
  #pragma unroll
  for(int mi = 0; mi < 8; mi++){
    int prb = m0 + wm*128 + mi*16 + quad*4;
    #pragma unroll
    for(int i = 0; i < 4; i++){
      int pr = prb + i;
      if(pr < cnt){
        int gp = off + pr;
        float wt = pair_wt[gp];
        float* prow = pout + (size_t)gp * DMODEL + n0 + wn*64 + lm;
        #pragma unroll
        for(int ni = 0; ni < 4; ni++)
          __builtin_nontemporal_store(acc[mi][ni][i] * wt, prow + ni*16);
      }
    }
  }
}

// ---------------- combine: out[t] = pout[p0(t)] + pout[p1(t)] ----------------
__global__ void k_combine(const float4* __restrict__ pout, const int* __restrict__ t2p,
                          float4* __restrict__ out){
  int t = blockIdx.x;
  int d = threadIdx.x;                       // 256 threads x float4 = 1024 floats
  int p0 = t2p[2*t], p1 = t2p[2*t + 1];
  out[(size_t)t * 256 + d] = pout[(size_t)p0 * 256 + d] + pout[(size_t)p1 * 256 + d];
}

extern "C" void kernel_launch(void* const* d_in, const int* in_sizes, int n_in,
                              void* d_out, int out_size, void* d_ws, size_t ws_size,
                              hipStream_t stream){
  const float* x  = (const float*)d_in[0];
  const float* gw = (const float*)d_in[1];
  const float* w1 = (const float*)d_in[2];
  const float* w3 = (const float*)d_in[3];
  const float* w2 = (const float*)d_in[4];
  float* out = (float*)d_out;

  char* ws = (char*)d_ws;
  size_t o = 0;
  auto alloc = [&](size_t b){ size_t r = o; o += (b + 255) & ~(size_t)255; return r; };
  unsigned short* xb  = (unsigned short*)(ws + alloc((size_t)NTOK * DMODEL * 2));
  unsigned short* w1t = (unsigned short*)(ws + alloc((size_t)NEXP * DMODEL * FDIM * 2));
  unsigned short* w3t = (unsigned short*)(ws + alloc((size_t)NEXP * DMODEL * FDIM * 2));
  unsigned short* w2t = (unsigned short*)(ws + alloc((size_t)NEXP * DMODEL * FDIM * 2));
  unsigned short* h   = (unsigned short*)(ws + alloc((size_t)2 * NTOK * FDIM * 2));
  int*   route_e  = (int*)  (ws + alloc(2 * NTOK * 4));
  float* route_w  = (float*)(ws + alloc(2 * NTOK * 4));
  int*   counts   = (int*)  (ws + alloc(256));
  int*   offsets  = (int*)  (ws + alloc(256));
  int*   cursor   = (int*)  (ws + alloc(256));
  int*   pair_tok = (int*)  (ws + alloc(2 * NTOK * 4));
  float* pair_wt  = (float*)(ws + alloc(2 * NTOK * 4));
  int*   t2p      = (int*)  (ws + alloc(2 * NTOK * 4));
  // pout [2*NTOK][DMODEL] fp32 = 64MB aliases w1t (64MB): w1t dead after ffn1.
  float* pout = (float*)w1t;

  hipMemsetAsync(counts, 0, 256, stream);

  // bf16 conversions / weight transposes to [n][k] layout
  k_cvt<<<2048, 256, 0, stream>>>((const float4*)x, (ushort4*)xb, NTOK * DMODEL / 4);
  k_tr<<<dim3(FDIM/64, DMODEL/64, NEXP), 256, 0, stream>>>(w1, w1t, DMODEL, FDIM);
  k_tr<<<dim3(FDIM/64, DMODEL/64, NEXP), 256, 0, stream>>>(w3, w3t, DMODEL, FDIM);
  k_tr<<<dim3(DMODEL/64, FDIM/64, NEXP), 256, 0, stream>>>(w2, w2t, FDIM, DMODEL);

  // routing
  k_router<<<NTOK/4, 256, 0, stream>>>(x, gw, route_e, route_w, counts);
  k_scan<<<1, 64, 0, stream>>>(counts, offsets, cursor);
  k_fill<<<NTOK/256, 256, 0, stream>>>(route_e, route_w, offsets, cursor, pair_tok, pair_wt, t2p);

  // grouped GEMMs (worst-case grid; blocks past cnt exit early)
  k_ffn1<<<dim3(64, FDIM/128, NEXP), 512, 0, stream>>>(xb, w1t, w3t, counts, offsets, pair_tok, h);
  k_ffn2<<<dim3(64, DMODEL/256, NEXP), 512, 0, stream>>>(h, w2t, counts, offsets, pair_wt, pout);
  k_combine<<<NTOK, 256, 0, stream>>>((const float4*)pout, t2p, (float4*)out);
}